// Round 1
// baseline (527.418 us; speedup 1.0000x reference)
//
#include <hip/hip_runtime.h>
#include <math.h>

#define L_SEQ 16384
#define NB 2
#define CDIM 64
#define DIN 128
#define DST 16
#define NCHK 128   // number of scan chunks
#define CLEN 128   // chunk length
#define HIDC 170
#define H2 340

__device__ __forceinline__ float sigmoidf_(float x){ return 1.f/(1.f+__expf(-x)); }
__device__ __forceinline__ float siluf_(float x){ return x*sigmoidf_(x); }
__device__ __forceinline__ float softplusf_(float x){ return x>20.f ? x : log1pf(__expf(x)); }
__device__ __forceinline__ float geluf_(float x){ return 0.5f*x*(1.f+erff(x*0.70710678118654752f)); }

// ---------------- K0: A = -exp(A_log) ----------------
__global__ void k_prep_A(const float* __restrict__ Alog, float* __restrict__ Aneg){
    int i = blockIdx.x*256 + threadIdx.x;
    if(i < DIN*DST) Aneg[i] = -__expf(Alog[i]);
}

// ---------------- K1: LN1, NCHW -> token-major (b,l,c) ----------------
__global__ void k_ln1(const float* __restrict__ x, const float* __restrict__ w,
                      const float* __restrict__ bb, float* __restrict__ tok){
    __shared__ float t[64][65];
    int blk = blockIdx.x; int b = blk >> 8; int l0 = (blk & 255) << 6;
    int tid = threadIdx.x;
    const float* xb = x + (size_t)b*CDIM*L_SEQ;
    for(int c=0;c<64;c++) t[c][tid] = xb[(size_t)c*L_SEQ + l0 + tid];
    __syncthreads();
    float s=0.f, s2=0.f;
    for(int c=0;c<64;c++){ float v=t[c][tid]; s+=v; s2+=v*v; }
    float mu = s*(1.f/64.f);
    float var = s2*(1.f/64.f) - mu*mu;
    float r = rsqrtf(var + 1e-5f);
    for(int c=0;c<64;c++) t[c][tid] = (t[c][tid]-mu)*r*w[c] + bb[c];
    __syncthreads();
    float* tb = tok + (size_t)b*L_SEQ*64;
    for(int l=0;l<64;l++) tb[(size_t)(l0+l)*64 + tid] = t[tid][l];
}

// ---------------- generic GEMM: C[M][N] = A[M][K] * W[N][K]^T ----------------
template<int N, int K, int NT>
__global__ void gemm_nt(const float* __restrict__ A, const float* __restrict__ W,
                        float* __restrict__ C, int M){
    __shared__ float As[64][K+4];
    __shared__ float Ws[NT][K+4];
    int tid = threadIdx.x; int m0 = blockIdx.x*64;
    for(int i=tid;i<64*K;i+=256){ int r=i/K, k=i-r*K; As[r][k] = A[(size_t)(m0+r)*K + k]; }
    int l = tid>>2, sub = tid&3;
    for(int nb=0;nb<N;nb+=NT){
        __syncthreads();
        for(int i=tid;i<NT*K;i+=256){ int n=i/K, k=i-n*K; Ws[n][k] = W[(size_t)(nb+n)*K + k]; }
        __syncthreads();
        for(int n=sub;n<NT;n+=4){
            float acc = 0.f;
            #pragma unroll 8
            for(int k=0;k<K;k++) acc += As[l][k]*Ws[n][k];
            C[(size_t)(m0+l)*N + nb + n] = acc;
        }
    }
}

// ---------------- K3: causal depthwise conv1d(k=4)+bias+SiLU ----------------
__global__ void k_conv_silu(const float* __restrict__ xz, const float* __restrict__ cw,
                            const float* __restrict__ cb, float* __restrict__ xc){
    int idx = blockIdx.x*256 + threadIdx.x;
    int d = idx & 127; int lpos = (idx >> 7) & (L_SEQ-1); int b = idx >> 21;
    const float* base = xz + (size_t)b*L_SEQ*256;
    float acc = cb[d];
    #pragma unroll
    for(int k=0;k<4;k++){
        int t = lpos-3+k;
        if(t>=0) acc += base[(size_t)t*256 + d]*cw[d*4+k];
    }
    xc[idx] = siluf_(acc);
}

// ---------------- K5: dt = softplus(dt_r @ dtw^T + dtb) ----------------
__global__ void k_dt(const float* __restrict__ dbc, const float* __restrict__ dtw,
                     const float* __restrict__ dtb, float* __restrict__ dt){
    int idx = blockIdx.x*256 + threadIdx.x;
    int d = idx & 127; int row = idx >> 7;
    const float* r = dbc + (size_t)row*36;
    float v = r[0]*dtw[d*4] + r[1]*dtw[d*4+1] + r[2]*dtw[d*4+2] + r[3]*dtw[d*4+3] + dtb[d];
    dt[idx] = softplusf_(v);
}

// ---------------- K6: scan phase 1: per-chunk (Aprod, zero-state F) ----------------
__global__ void k_scan1(const float* __restrict__ dt, const float* __restrict__ xc,
                        const float* __restrict__ dbc, const float* __restrict__ Aneg,
                        float* __restrict__ Pg, float* __restrict__ Fg){
    __shared__ float Bs[CLEN][DST];
    int blk = blockIdx.x; int c = blk >> 1; int b = blk & 1;
    int d = threadIdx.x; int t0 = c*CLEN;
    {
        int t = d;
        const float* rr = dbc + ((size_t)(b*L_SEQ + t0 + t))*36 + 4;
        for(int s=0;s<16;s++) Bs[t][s] = rr[s];
    }
    float Ar[16];
    #pragma unroll
    for(int s=0;s<16;s++) Ar[s] = Aneg[d*16+s];
    float Pr[16], Fr[16];
    #pragma unroll
    for(int s=0;s<16;s++){ Pr[s]=1.f; Fr[s]=0.f; }
    __syncthreads();
    const float* dtp = dt + ((size_t)(b*L_SEQ + t0))*DIN + d;
    const float* xcp = xc + ((size_t)(b*L_SEQ + t0))*DIN + d;
    for(int t=0;t<CLEN;t++){
        float dtv = dtp[(size_t)t*DIN];
        float xv  = xcp[(size_t)t*DIN];
        float du = dtv*xv;
        #pragma unroll
        for(int s=0;s<16;s++){
            float e = __expf(dtv*Ar[s]);
            Fr[s] = e*Fr[s] + du*Bs[t][s];
            Pr[s] *= e;
        }
    }
    int st = (b*DIN + d)*DST;
    float* Pp = Pg + (size_t)c*4096 + st;
    float* Fp = Fg + (size_t)c*4096 + st;
    #pragma unroll
    for(int s=0;s<16;s++){ Pp[s]=Pr[s]; Fp[s]=Fr[s]; }
}

// ---------------- K7: scan phase 2: sequential chunk combine ----------------
__global__ void k_scan2(const float* __restrict__ Pg, const float* __restrict__ Fg,
                        float* __restrict__ Hin){
    int st = blockIdx.x*256 + threadIdx.x;
    if(st >= 4096) return;
    float H = 0.f;
    for(int c=0;c<NCHK;c++){
        Hin[(size_t)c*4096 + st] = H;
        H = Pg[(size_t)c*4096 + st]*H + Fg[(size_t)c*4096 + st];
    }
}

// ---------------- K8: scan phase 3: recompute with carry, fuse gate ----------------
__global__ void k_scan3(const float* __restrict__ dt, const float* __restrict__ xc,
                        const float* __restrict__ dbc, const float* __restrict__ Aneg,
                        const float* __restrict__ Hin, const float* __restrict__ xz,
                        const float* __restrict__ Dskip, float* __restrict__ y2){
    __shared__ float Bs[CLEN][DST];
    __shared__ float Cs[CLEN][DST];
    int blk = blockIdx.x; int c = blk >> 1; int b = blk & 1;
    int d = threadIdx.x; int t0 = c*CLEN;
    {
        int t = d;
        const float* rr = dbc + ((size_t)(b*L_SEQ + t0 + t))*36;
        for(int s=0;s<16;s++){ Bs[t][s] = rr[4+s]; Cs[t][s] = rr[20+s]; }
    }
    float Ar[16];
    #pragma unroll
    for(int s=0;s<16;s++) Ar[s] = Aneg[d*16+s];
    float h[16];
    {
        int st = (b*DIN + d)*DST;
        const float* hp = Hin + (size_t)c*4096 + st;
        #pragma unroll
        for(int s=0;s<16;s++) h[s] = hp[s];
    }
    float Dv = Dskip[d];
    __syncthreads();
    const size_t rowbase = (size_t)(b*L_SEQ + t0);
    for(int t=0;t<CLEN;t++){
        size_t row = rowbase + t;
        float dtv = dt[row*DIN + d];
        float xv  = xc[row*DIN + d];
        float du = dtv*xv;
        float y = 0.f;
        #pragma unroll
        for(int s=0;s<16;s++){
            float e = __expf(dtv*Ar[s]);
            h[s] = e*h[s] + du*Bs[t][s];
            y += h[s]*Cs[t][s];
        }
        float zv = xz[row*256 + 128 + d];
        y2[row*DIN + d] = (y + Dv*xv)*siluf_(zv);
    }
}

// ---------------- K10: residual + LN2 -> x1 (NCHW) and x2 (token) ----------------
__global__ void k_res_ln2(const float* __restrict__ x, const float* __restrict__ mo,
                          const float* __restrict__ w2, const float* __restrict__ b2,
                          float* __restrict__ x1, float* __restrict__ x2){
    __shared__ float tA[64][65];
    __shared__ float tB[64][65];
    int blk = blockIdx.x; int b = blk >> 8; int l0 = (blk & 255) << 6;
    int tid = threadIdx.x;
    const float* mob = mo + (size_t)b*L_SEQ*64;
    for(int r=0;r<64;r++) tB[tid][r] = mob[(size_t)(l0+r)*64 + tid];
    __syncthreads();
    const float* xb = x + (size_t)b*64*L_SEQ;
    float* x1b = x1 + (size_t)b*64*L_SEQ;
    float s=0.f, s2=0.f;
    for(int c=0;c<64;c++){
        float v = xb[(size_t)c*L_SEQ + l0 + tid] + tB[c][tid];
        x1b[(size_t)c*L_SEQ + l0 + tid] = v;
        tA[c][tid] = v; s += v; s2 += v*v;
    }
    float mu = s*(1.f/64.f);
    float var = s2*(1.f/64.f) - mu*mu;
    float r = rsqrtf(var + 1e-5f);
    for(int c=0;c<64;c++) tA[c][tid] = (tA[c][tid]-mu)*r*w2[c] + b2[c];
    __syncthreads();
    float* x2b = x2 + (size_t)b*L_SEQ*64;
    for(int l=0;l<64;l++) x2b[(size_t)(l0+l)*64 + tid] = tA[tid][l];
}

// ---------------- K12: depthwise 3x3 + GELU gate ----------------
__global__ void k_dw_gate(const float* __restrict__ h, const float* __restrict__ wdw,
                          float* __restrict__ g){
    int idx = blockIdx.x*256 + threadIdx.x;
    if(idx >= NB*L_SEQ*HIDC) return;
    int j = idx % HIDC; int p = (idx / HIDC) & (L_SEQ-1); int b = idx / (HIDC*L_SEQ);
    int y0 = p >> 7, x0 = p & 127;
    const float* hb = h + (size_t)b*L_SEQ*H2;
    float a1=0.f, a2=0.f;
    #pragma unroll
    for(int ky=0;ky<3;ky++){
        int yy = y0+ky-1; if(yy<0 || yy>127) continue;
        #pragma unroll
        for(int kx=0;kx<3;kx++){
            int xx = x0+kx-1; if(xx<0 || xx>127) continue;
            const float* hp = hb + ((size_t)(yy*128+xx))*H2;
            a1 += hp[j]        * wdw[j*9 + ky*3+kx];
            a2 += hp[j+HIDC]   * wdw[(j+HIDC)*9 + ky*3+kx];
        }
    }
    g[idx] = geluf_(a1)*a2;
}

// ---------------- K14: final residual, token->NCHW ----------------
__global__ void k_final(const float* __restrict__ x1, const float* __restrict__ o2,
                        float* __restrict__ out){
    __shared__ float tB[64][65];
    int blk = blockIdx.x; int b = blk >> 8; int l0 = (blk & 255) << 6;
    int tid = threadIdx.x;
    const float* ob = o2 + (size_t)b*L_SEQ*64;
    for(int r=0;r<64;r++) tB[tid][r] = ob[(size_t)(l0+r)*64 + tid];
    __syncthreads();
    const float* x1b = x1 + (size_t)b*64*L_SEQ;
    float* outb = out + (size_t)b*64*L_SEQ;
    for(int c=0;c<64;c++)
        outb[(size_t)c*L_SEQ + l0 + tid] = x1b[(size_t)c*L_SEQ + l0 + tid] + tB[c][tid];
}

extern "C" void kernel_launch(void* const* d_in, const int* in_sizes, int n_in,
                              void* d_out, int out_size, void* d_ws, size_t ws_size,
                              hipStream_t stream) {
    const float* x        = (const float*)d_in[0];
    const float* ln1_w    = (const float*)d_in[1];
    const float* ln1_b    = (const float*)d_in[2];
    const float* in_proj  = (const float*)d_in[3];
    const float* conv_w   = (const float*)d_in[4];
    const float* conv_b   = (const float*)d_in[5];
    const float* xproj_w  = (const float*)d_in[6];
    const float* dt_w     = (const float*)d_in[7];
    const float* dt_b     = (const float*)d_in[8];
    const float* A_log    = (const float*)d_in[9];
    const float* D_skip   = (const float*)d_in[10];
    const float* outp_w   = (const float*)d_in[11];
    const float* ln2_w    = (const float*)d_in[12];
    const float* ln2_b    = (const float*)d_in[13];
    const float* gin_w    = (const float*)d_in[14];
    const float* gdw_w    = (const float*)d_in[15];
    const float* gout_w   = (const float*)d_in[16];
    float* out = (float*)d_out;
    float* ws = (float*)d_ws;

    const int M = NB*L_SEQ; // 32768
    size_t o = 0;
    float* Aneg = ws + o; o += 2048;
    float* tok  = ws + o; o += (size_t)M*64;        // reused as mamba_out
    float* xz   = ws + o; o += (size_t)M*256;       // reused as gdfn h (spills into xc region)
    float* xc   = ws + o; o += (size_t)M*128;
    float* dbc  = ws + o; o += (size_t)M*36;
    float* dtb_ = ws + o; o += (size_t)M*128;       // reused as gdfn g (spills into y2 region)
    float* y2   = ws + o; o += (size_t)M*128;
    float* Pg   = ws + o; o += (size_t)NCHK*4096;
    float* Fg   = ws + o; o += (size_t)NCHK*4096;
    float* Hin  = ws + o; o += (size_t)NCHK*4096;
    float* x1   = ws + o; o += (size_t)M*64;
    float* x2   = ws + o; o += (size_t)M*64;
    float* out2 = ws + o; o += (size_t)M*64;
    float* mo   = tok;    // mamba out_proj output (tok dead)
    float* hbuf = xz;     // gdfn hidden (xz/xc dead)
    float* gbuf = dtb_;   // gdfn gated (dt/y2 dead)

    k_prep_A<<<8,256,0,stream>>>(A_log, Aneg);
    k_ln1<<<512,64,0,stream>>>(x, ln1_w, ln1_b, tok);
    gemm_nt<256,64,128><<<512,256,0,stream>>>(tok, in_proj, xz, M);
    k_conv_silu<<<M*128/256,256,0,stream>>>(xz, conv_w, conv_b, xc);
    gemm_nt<36,128,36><<<512,256,0,stream>>>(xc, xproj_w, dbc, M);
    k_dt<<<M*128/256,256,0,stream>>>(dbc, dt_w, dt_b, dtb_);
    k_scan1<<<256,128,0,stream>>>(dtb_, xc, dbc, Aneg, Pg, Fg);
    k_scan2<<<16,256,0,stream>>>(Pg, Fg, Hin);
    k_scan3<<<256,128,0,stream>>>(dtb_, xc, dbc, Aneg, Hin, xz, D_skip, y2);
    gemm_nt<64,128,32><<<512,256,0,stream>>>(y2, outp_w, mo, M);
    k_res_ln2<<<512,64,0,stream>>>(x, mo, ln2_w, ln2_b, x1, x2);
    gemm_nt<340,64,170><<<512,256,0,stream>>>(x2, gin_w, hbuf, M);
    k_dw_gate<<<(M*HIDC+255)/256,256,0,stream>>>(hbuf, gdw_w, gbuf);
    gemm_nt<64,170,16><<<512,256,0,stream>>>(gbuf, gout_w, out2, M);
    k_final<<<512,64,0,stream>>>(x1, out2, out);
}